// Round 3
// baseline (277.163 us; speedup 1.0000x reference)
//
#include <hip/hip_runtime.h>

// LinearTimeMMDLoss: m=65536, d=512, m2=32768 pairs.
// One wave per pair (32768 waves): 8 coalesced float4 loads -> one 6-level
// butterfly -> 20 exp terms spread across lanes -> block partial -> final
// reduce kernel. Maximize wave count / MLP: latency-bound fix.

#define D        512
#define M2       32768
#define NTHREADS 256
#define WPB      (NTHREADS / 64)      // 4 waves (pairs) per block
#define NBLOCKS  (M2 / WPB)           // 8192 blocks, exact cover

__global__ __launch_bounds__(NTHREADS, 8) void mmd_pairs(const float* __restrict__ src,
                                                         const float* __restrict__ tgt,
                                                         float* __restrict__ partial) {
    const int lane = threadIdx.x & 63;
    const int wid  = threadIdx.x >> 6;
    const int pair = blockIdx.x * WPB + wid;

    const float* xo = src + (size_t)(2 * D) * (size_t)pair;
    const float* xe = xo + D;
    const float* yo = tgt + (size_t)(2 * D) * (size_t)pair;
    const float* ye = yo + D;

    float sxx = 0.f, syy = 0.f, sxy = 0.f, syx = 0.f;

    // 64 lanes x (2 x float4) = 512 floats per row, fully coalesced.
#pragma unroll
    for (int c = 0; c < 2; ++c) {
        const int idx = c * 256 + lane * 4;
        const float4 a  = *reinterpret_cast<const float4*>(xo + idx);
        const float4 b  = *reinterpret_cast<const float4*>(xe + idx);
        const float4 g  = *reinterpret_cast<const float4*>(yo + idx);
        const float4 h4 = *reinterpret_cast<const float4*>(ye + idx);
#define COMP(f)                                   \
        { float t;                                \
          t = a.f - b.f;   sxx += t * t;          \
          t = g.f - h4.f;  syy += t * t;          \
          t = a.f - h4.f;  sxy += t * t;          \
          t = b.f - g.f;   syx += t * t; }
        COMP(x) COMP(y) COMP(z) COMP(w)
#undef COMP
    }

    // Wave-wide butterfly: all lanes end up with the four full sums.
#pragma unroll
    for (int off = 32; off > 0; off >>= 1) {
        sxx += __shfl_xor(sxx, off, 64);
        syy += __shfl_xor(syy, off, 64);
        sxy += __shfl_xor(sxy, off, 64);
        syx += __shfl_xor(syx, off, 64);
    }

    // 20 exp terms distributed: r=lane&3 picks distance, k=lane>>2 picks bw.
    const int   r    = lane & 3;             // 0:dxx 1:dyy 2:dxy 3:dyx
    const int   k    = lane >> 2;
    const float mult = (float)(1 << k);
    const float sgn  = (k < 5) ? ((r < 2) ? 1.0f : -1.0f) : 0.0f;

    // bw = (sum of 4 distances)/4 / 2^(5//2) = sum/16
    const float bw   = (sxx + syy + sxy + syx) * 0.0625f;
    const float bws  = bw * mult + 1e-6f;
    const float dsel = (r & 2) ? ((r & 1) ? syx : sxy)
                               : ((r & 1) ? syy : sxx);
    float acc = sgn * expf(-dsel / bws);     // sgn==0 masks lanes 20..63

    // Reduce the 20 terms across the wave, then across the block's 4 waves.
#pragma unroll
    for (int off = 32; off > 0; off >>= 1) acc += __shfl_xor(acc, off, 64);

    __shared__ float red[WPB];
    if (lane == 0) red[wid] = acc;
    __syncthreads();
    if (threadIdx.x == 0) {
        float s = 0.f;
#pragma unroll
        for (int i = 0; i < WPB; ++i) s += red[i];
        partial[blockIdx.x] = s;
    }
}

__global__ __launch_bounds__(256) void mmd_final(const float* __restrict__ partial,
                                                 float* __restrict__ out) {
    float s = 0.f;
    for (int i = threadIdx.x; i < NBLOCKS; i += 256) s += partial[i];
#pragma unroll
    for (int off = 32; off > 0; off >>= 1) s += __shfl_xor(s, off, 64);
    __shared__ float red[4];
    if ((threadIdx.x & 63) == 0) red[threadIdx.x >> 6] = s;
    __syncthreads();
    if (threadIdx.x == 0)
        out[0] = (red[0] + red[1] + red[2] + red[3]) * (1.0f / (float)M2);
}

extern "C" void kernel_launch(void* const* d_in, const int* in_sizes, int n_in,
                              void* d_out, int out_size, void* d_ws, size_t ws_size,
                              hipStream_t stream) {
    const float* src = (const float*)d_in[0];
    const float* tgt = (const float*)d_in[1];
    float* out = (float*)d_out;
    float* partial = (float*)d_ws;  // NBLOCKS floats = 32 KiB, fully written before read

    mmd_pairs<<<NBLOCKS, NTHREADS, 0, stream>>>(src, tgt, partial);
    mmd_final<<<1, 256, 0, stream>>>(partial, out);
}

// Round 6
// 270.967 us; speedup vs baseline: 1.0229x; 1.0229x over previous
//
#include <hip/hip_runtime.h>

// LinearTimeMMDLoss: m=65536, d=512, m2=32768 pairs.
// Frozen arithmetic (absmax 0.0 in R1/R2): per-lane 8-element partials at
// idx=c*256+lane*4, interleaved 6-level __shfl_xor butterfly, 64-lane
// distributed epilogue (r=lane&3, k=lane>>2, sgn=0 for k>=5), 2048-block
// partials + final reduce kernel.
// Perf change: 4 pairs per wave with chunk-batched loads (16 independent
// float4 loads in flight before any consumption) -> restore per-wave MLP
// that the VGPR=20 allocation destroyed in R1-R3.

#define D        512
#define M2       32768
#define NTHREADS 256
#define WPB      (NTHREADS / 64)        // 4 waves per block
#define P        4                      // pairs per wave
#define NBLOCKS  (M2 / (WPB * P))       // 2048 blocks, exact cover

__global__ __launch_bounds__(NTHREADS, 4) void mmd_pairs(const float* __restrict__ src,
                                                         const float* __restrict__ tgt,
                                                         float* __restrict__ partial) {
    const int lane = threadIdx.x & 63;
    const int wid  = threadIdx.x >> 6;
    const int wave = blockIdx.x * WPB + wid;
    const int base = wave * P;          // this wave's 4 contiguous pairs

    float sxx[P], syy[P], sxy[P], syx[P];
#pragma unroll
    for (int i = 0; i < P; ++i) { sxx[i] = 0.f; syy[i] = 0.f; sxy[i] = 0.f; syx[i] = 0.f; }

    // Streaming phase: per chunk, issue all 16 loads (4 rows x 4 pairs) before
    // consuming any. Same per-pair element->lane map and FMA order as R1/R2.
#pragma unroll
    for (int c = 0; c < 2; ++c) {
        const int idx = c * 256 + lane * 4;
        float4 a[P], b[P], g[P], h4[P];
#pragma unroll
        for (int i = 0; i < P; ++i) {
            const float* xo = src + (size_t)(2 * D) * (size_t)(base + i);
            const float* yo = tgt + (size_t)(2 * D) * (size_t)(base + i);
            a[i]  = *reinterpret_cast<const float4*>(xo + idx);
            b[i]  = *reinterpret_cast<const float4*>(xo + D + idx);
            g[i]  = *reinterpret_cast<const float4*>(yo + idx);
            h4[i] = *reinterpret_cast<const float4*>(yo + D + idx);
        }
#pragma unroll
        for (int i = 0; i < P; ++i) {
#define COMP(f)                                          \
            { float t;                                   \
              t = a[i].f - b[i].f;   sxx[i] += t * t;    \
              t = g[i].f - h4[i].f;  syy[i] += t * t;    \
              t = a[i].f - h4[i].f;  sxy[i] += t * t;    \
              t = b[i].f - g[i].f;   syx[i] += t * t; }
            COMP(x) COMP(y) COMP(z) COMP(w)
#undef COMP
        }
    }

    // Reduction + epilogue phase (off the load critical path).
    const int   r    = lane & 3;             // 0:dxx 1:dyy 2:dxy 3:dyx
    const int   k    = lane >> 2;
    const float mult = (float)(1 << k);
    const float sgn  = (k < 5) ? ((r < 2) ? 1.0f : -1.0f) : 0.0f;

    float acc = 0.0f;
#pragma unroll
    for (int i = 0; i < P; ++i) {
        float xx = sxx[i], yy = syy[i], xy = sxy[i], yx = syx[i];
#pragma unroll
        for (int off = 32; off > 0; off >>= 1) {
            xx += __shfl_xor(xx, off, 64);
            yy += __shfl_xor(yy, off, 64);
            xy += __shfl_xor(xy, off, 64);
            yx += __shfl_xor(yx, off, 64);
        }
        // bw = (dxx+dyy+dxy+dyx)/4 / 2^(5//2) = sum/16
        const float bw   = (xx + yy + xy + yx) * 0.0625f;
        const float bws  = bw * mult + 1e-6f;
        const float dsel = (r & 2) ? ((r & 1) ? yx : xy)
                                   : ((r & 1) ? yy : xx);
        acc += sgn * expf(-dsel / bws);      // sgn==0 masks lanes 20..63
    }

    // Per-wave butterfly, then block reduction -> one partial per block.
#pragma unroll
    for (int off = 32; off > 0; off >>= 1) acc += __shfl_xor(acc, off, 64);

    __shared__ float red[WPB];
    if (lane == 0) red[wid] = acc;
    __syncthreads();
    if (threadIdx.x == 0) {
        float s = 0.f;
#pragma unroll
        for (int i = 0; i < WPB; ++i) s += red[i];
        partial[blockIdx.x] = s;
    }
}

__global__ __launch_bounds__(256) void mmd_final(const float* __restrict__ partial,
                                                 float* __restrict__ out) {
    float s = 0.f;
    for (int i = threadIdx.x; i < NBLOCKS; i += 256) s += partial[i];
#pragma unroll
    for (int off = 32; off > 0; off >>= 1) s += __shfl_xor(s, off, 64);
    __shared__ float red[4];
    if ((threadIdx.x & 63) == 0) red[threadIdx.x >> 6] = s;
    __syncthreads();
    if (threadIdx.x == 0)
        out[0] = (red[0] + red[1] + red[2] + red[3]) * (1.0f / (float)M2);
}

extern "C" void kernel_launch(void* const* d_in, const int* in_sizes, int n_in,
                              void* d_out, int out_size, void* d_ws, size_t ws_size,
                              hipStream_t stream) {
    const float* src = (const float*)d_in[0];
    const float* tgt = (const float*)d_in[1];
    float* out = (float*)d_out;
    float* partial = (float*)d_ws;  // NBLOCKS floats = 8 KiB, fully written before read

    mmd_pairs<<<NBLOCKS, NTHREADS, 0, stream>>>(src, tgt, partial);
    mmd_final<<<1, 256, 0, stream>>>(partial, out);
}